// Round 5
// baseline (251.077 us; speedup 1.0000x reference)
//
#include <hip/hip_runtime.h>

#define BB 8
#define TT 2048
#define EE 1024
#define HH 128

typedef __bf16 bf16;
typedef __attribute__((ext_vector_type(8))) __bf16 bf16x8;
typedef __attribute__((ext_vector_type(4))) float f32x4;

// chunk=2 split bookkeeping over 64-row q-blocks: ns(qb)=(qb>>1)+1
__device__ __host__ inline int qb_off32(int qb) {
  int h = qb >> 1;
  return qb + h * (h - 1) + ((qb & 1) ? h : 0);
}
#define NSLAB 272  // qb_off32(32)

// ---- Wt[z*128+n][k] = W_z[k][n], fp32->bf16, LDS transpose ----
__global__ __launch_bounds__(256) void wt_kernel(const float* __restrict__ wq,
                                                 const float* __restrict__ wk,
                                                 const float* __restrict__ wv,
                                                 bf16* __restrict__ wt) {
  __shared__ float tile[64][65];
  const int z = blockIdx.z;
  const float* w = (z == 0) ? wq : ((z == 1) ? wk : wv);
  const int k0 = blockIdx.x * 64;  // 16
  const int h0 = blockIdx.y * 64;  // 2
  const int c = threadIdx.x & 63;
  const int r0 = threadIdx.x >> 6;
#pragma unroll
  for (int i = 0; i < 16; ++i) {
    int tt = r0 + i * 4;
    tile[tt][c] = w[(size_t)(k0 + tt) * HH + h0 + c];
  }
  __syncthreads();
#pragma unroll
  for (int i = 0; i < 16; ++i) {
    int hh = r0 + i * 4;
    wt[((size_t)(z * HH + h0 + hh)) * EE + k0 + c] = (bf16)tile[c][hh];
  }
}

// ---- fused qkv GEMM, barrier-free dataflow ----
// block = 4 waves, 32 rows x 384 cols; wave = 32 rows x 96 cols (col quarter).
// A-frags direct from global x (fp32->cvt), W-frags from L1/L2; no LDS.
__global__ __launch_bounds__(256, 4) void qkv_kernel(const float* __restrict__ x,
                                                     const bf16* __restrict__ wt,
                                                     bf16* __restrict__ q,
                                                     bf16* __restrict__ k,
                                                     bf16* __restrict__ v) {
  const int lane = threadIdx.x & 63;
  const int wave = threadIdx.x >> 6;
  const int l16 = lane & 15;
  const int quad = lane >> 4;
  const int row0 = blockIdx.x * 32;

  const float* xb = x + (size_t)(row0 + l16) * EE + quad * 8;
  const bf16* wb = wt + (size_t)(wave * 96 + l16) * EE + quad * 8;

  f32x4 acc[2][6];
#pragma unroll
  for (int rg = 0; rg < 2; ++rg)
#pragma unroll
    for (int nt = 0; nt < 6; ++nt) acc[rg][nt] = f32x4{0.f, 0.f, 0.f, 0.f};

  for (int ks = 0; ks < EE / 32; ++ks) {
    f32x4 a00 = *(const f32x4*)(xb + ks * 32);
    f32x4 a01 = *(const f32x4*)(xb + ks * 32 + 4);
    f32x4 a10 = *(const f32x4*)(xb + (size_t)16 * EE + ks * 32);
    f32x4 a11 = *(const f32x4*)(xb + (size_t)16 * EE + ks * 32 + 4);
    bf16x8 af0, af1;
#pragma unroll
    for (int j = 0; j < 4; ++j) {
      af0[j] = (bf16)a00[j]; af0[j + 4] = (bf16)a01[j];
      af1[j] = (bf16)a10[j]; af1[j + 4] = (bf16)a11[j];
    }
#pragma unroll
    for (int nt = 0; nt < 6; ++nt) {
      bf16x8 bfr = *(const bf16x8*)(wb + (size_t)(nt * 16) * EE + ks * 32);
      acc[0][nt] = __builtin_amdgcn_mfma_f32_16x16x32_bf16(af0, bfr, acc[0][nt], 0, 0, 0);
      acc[1][nt] = __builtin_amdgcn_mfma_f32_16x16x32_bf16(af1, bfr, acc[1][nt], 0, 0, 0);
    }
  }

  bf16* outp[3] = {q, k, v};
#pragma unroll
  for (int rg = 0; rg < 2; ++rg)
#pragma unroll
    for (int nt = 0; nt < 6; ++nt) {
      int col = wave * 96 + nt * 16 + l16;
      int z = col >> 7;
      int n = col & 127;
#pragma unroll
      for (int r = 0; r < 4; ++r) {
        int row = row0 + rg * 16 + quad * 4 + r;
        outp[z][(size_t)row * HH + n] = (bf16)acc[rg][nt][r];
      }
    }
}

// ---- vt[b][h][t] = v[b][t][h] ----
__global__ __launch_bounds__(256) void vtrans_kernel(const bf16* __restrict__ v,
                                                     bf16* __restrict__ vt) {
  __shared__ bf16 tile[64][65];
  const int b = blockIdx.z;
  const int t0 = blockIdx.x * 64;
  const int h0 = blockIdx.y * 64;
  const int c = threadIdx.x & 63;
  const int r0 = threadIdx.x >> 6;
#pragma unroll
  for (int i = 0; i < 16; ++i) {
    int tt = r0 + i * 4;
    tile[tt][c] = v[((size_t)(b * TT + t0 + tt)) * HH + h0 + c];
  }
  __syncthreads();
#pragma unroll
  for (int i = 0; i < 16; ++i) {
    int hh = r0 + i * 4;
    vt[((size_t)(b * HH + h0 + hh)) * TT + t0 + c] = tile[c][hh];
  }
}

// ---- flash, no-max softmax, l via ones-MFMA, no barriers ----
// block: 2 waves, 64 q-rows; wave: 32 rows. chunk = 2 k-tiles.
__global__ __launch_bounds__(128) void flash_kernel(const bf16* __restrict__ q,
                                                    const bf16* __restrict__ k,
                                                    const bf16* __restrict__ vt,
                                                    bf16* __restrict__ opart,
                                                    float* __restrict__ lpart) {
  const int qb = blockIdx.x;  // 64-row group, 0..31
  const int b = blockIdx.y;
  const int s = blockIdx.z;
  const int smax = qb >> 1;
  if (s > smax) return;
  const int kt0 = 2 * s;
  const int kt1 = min(2 * s + 1, qb);

  const int lane = threadIdx.x & 63;
  const int wave = threadIdx.x >> 6;
  const int l16 = lane & 15;
  const int quad = lane >> 4;
  const int wrow0 = qb * 64 + wave * 32;

  __shared__ float pbuf[2][32 * 68];
  float* pb = &pbuf[wave][0];

  bf16x8 qf[2][4];
#pragma unroll
  for (int rg = 0; rg < 2; ++rg) {
    const bf16* qbp = q + (size_t)(b * TT + wrow0 + rg * 16 + l16) * HH + quad * 8;
#pragma unroll
    for (int ks = 0; ks < 4; ++ks) qf[rg][ks] = *(const bf16x8*)(qbp + ks * 32);
  }

  f32x4 O[2][8];
#pragma unroll
  for (int rg = 0; rg < 2; ++rg)
#pragma unroll
    for (int nt = 0; nt < 8; ++nt) O[rg][nt] = f32x4{0.f, 0.f, 0.f, 0.f};
  f32x4 O9[2] = {f32x4{0.f, 0.f, 0.f, 0.f}, f32x4{0.f, 0.f, 0.f, 0.f}};

  bf16x8 ones;
  {
    bf16 ov = (l16 == 0) ? (bf16)1.0f : (bf16)0.0f;
#pragma unroll
    for (int j = 0; j < 8; ++j) ones[j] = ov;
  }

  const float c_ = 0.12753257680406733f;  // log2(e)/sqrt(128)

  for (int kt = kt0; kt <= kt1; ++kt) {
    f32x4 S[2][4];
#pragma unroll
    for (int rg = 0; rg < 2; ++rg)
#pragma unroll
      for (int nt = 0; nt < 4; ++nt) S[rg][nt] = f32x4{0.f, 0.f, 0.f, 0.f};
    const bf16* kb = k + (size_t)(b * TT + kt * 64 + l16) * HH + quad * 8;
#pragma unroll
    for (int nt = 0; nt < 4; ++nt) {
      bf16x8 kf[4];
#pragma unroll
      for (int ks = 0; ks < 4; ++ks)
        kf[ks] = *(const bf16x8*)(kb + (size_t)nt * 16 * HH + ks * 32);
#pragma unroll
      for (int ks = 0; ks < 4; ++ks) {
        S[0][nt] = __builtin_amdgcn_mfma_f32_16x16x32_bf16(qf[0][ks], kf[ks], S[0][nt], 0, 0, 0);
        S[1][nt] = __builtin_amdgcn_mfma_f32_16x16x32_bf16(qf[1][ks], kf[ks], S[1][nt], 0, 0, 0);
      }
    }

#pragma unroll
    for (int rg = 0; rg < 2; ++rg)
#pragma unroll
      for (int nt = 0; nt < 4; ++nt) {
        int col = kt * 64 + nt * 16 + l16;
#pragma unroll
        for (int r = 0; r < 4; ++r) {
          int row = wrow0 + rg * 16 + quad * 4 + r;
          float p = (col <= row) ? exp2f(S[rg][nt][r] * c_) : 0.f;
          pb[(rg * 16 + quad * 4 + r) * 68 + nt * 16 + l16] = p;
        }
      }
    __asm__ volatile("s_waitcnt lgkmcnt(0)" ::: "memory");

#pragma unroll
    for (int ks2 = 0; ks2 < 2; ++ks2) {
      bf16x8 af[2];
#pragma unroll
      for (int rg = 0; rg < 2; ++rg) {
        const float* pr = &pb[(rg * 16 + l16) * 68 + ks2 * 32 + quad * 8];
        f32x4 a0 = *(const f32x4*)pr;
        f32x4 a1 = *(const f32x4*)(pr + 4);
#pragma unroll
        for (int j = 0; j < 4; ++j) { af[rg][j] = (bf16)a0[j]; af[rg][j + 4] = (bf16)a1[j]; }
      }
      const bf16* vb = vt + (size_t)(b * HH + l16) * TT + kt * 64 + ks2 * 32 + quad * 8;
#pragma unroll
      for (int nt = 0; nt < 8; ++nt) {
        bf16x8 vf = *(const bf16x8*)(vb + (size_t)nt * 16 * TT);
        O[0][nt] = __builtin_amdgcn_mfma_f32_16x16x32_bf16(af[0], vf, O[0][nt], 0, 0, 0);
        O[1][nt] = __builtin_amdgcn_mfma_f32_16x16x32_bf16(af[1], vf, O[1][nt], 0, 0, 0);
      }
      O9[0] = __builtin_amdgcn_mfma_f32_16x16x32_bf16(af[0], ones, O9[0], 0, 0, 0);
      O9[1] = __builtin_amdgcn_mfma_f32_16x16x32_bf16(af[1], ones, O9[1], 0, 0, 0);
    }
    __asm__ volatile("s_waitcnt lgkmcnt(0)" ::: "memory");
  }

  const size_t slab = (size_t)(b * NSLAB + qb_off32(qb) + s);
  bf16* op = opart + slab * (64 * 128);
#pragma unroll
  for (int rg = 0; rg < 2; ++rg)
#pragma unroll
    for (int nt = 0; nt < 8; ++nt)
#pragma unroll
      for (int r = 0; r < 4; ++r) {
        int row = wave * 32 + rg * 16 + quad * 4 + r;
        op[row * 128 + nt * 16 + l16] = (bf16)O[rg][nt][r];
      }
  if (l16 == 0) {
#pragma unroll
    for (int rg = 0; rg < 2; ++rg)
#pragma unroll
      for (int r = 0; r < 4; ++r)
        lpart[slab * 64 + wave * 32 + rg * 16 + quad * 4 + r] = O9[rg][r];
  }
}

// ---- combine: plain sum, divide by summed l. 1024 blocks. ----
__global__ __launch_bounds__(256) void combine_kernel(const bf16* __restrict__ opart,
                                                      const float* __restrict__ lpart,
                                                      float* __restrict__ out) {
  const int qt16 = blockIdx.x;  // 16-row group, 0..127
  const int b = blockIdx.y;
  const int row = threadIdx.x >> 4;        // 0..15
  const int colo = (threadIdx.x & 15) * 8; // 8 cols
  const int qb = qt16 >> 2;
  const int srow = (qt16 & 3) * 16 + row;  // row within 64-row slab
  const int ns = (qb >> 1) + 1;            // 1..16
  const size_t slab0 = (size_t)(b * NSLAB + qb_off32(qb));

  float acc[8];
#pragma unroll
  for (int j = 0; j < 8; ++j) acc[j] = 0.f;
  float L = 0.f;
  for (int s = 0; s < ns; ++s) {
    L += lpart[(slab0 + s) * 64 + srow];
    bf16x8 ov = *(const bf16x8*)(opart + (slab0 + s) * (64 * 128) + srow * 128 + colo);
#pragma unroll
    for (int j = 0; j < 8; ++j) acc[j] += (float)ov[j];
  }
  float invL = 1.f / L;
  float* o = out + ((size_t)(b * TT + qt16 * 16 + row)) * HH + colo;
  f32x4 o0, o1;
#pragma unroll
  for (int j = 0; j < 4; ++j) { o0[j] = acc[j] * invL; o1[j] = acc[j + 4] * invL; }
  *(f32x4*)o = o0;
  *(f32x4*)(o + 4) = o1;
}

extern "C" void kernel_launch(void* const* d_in, const int* in_sizes, int n_in,
                              void* d_out, int out_size, void* d_ws, size_t ws_size,
                              hipStream_t stream) {
  const float* x = (const float*)d_in[0];
  const float* wq = (const float*)d_in[1];
  const float* wk = (const float*)d_in[2];
  const float* wv = (const float*)d_in[3];
  float* out = (float*)d_out;

  char* ws = (char*)d_ws;
  const size_t NE = (size_t)BB * TT * HH;  // 2,097,152
  bf16* wt = (bf16*)ws;                    // 768 KB
  bf16* q = (bf16*)(ws + (1 << 20));       // 4 MB each
  bf16* k = q + NE;
  bf16* vt = k + NE;
  float* lpart = (float*)(vt + NE);        // 8*272*64*4 = 557 KB
  bf16* opart = (bf16*)((char*)lpart + 8 * NSLAB * 64 * sizeof(float));
  // opart: 8*272 slabs * 64*128 * 2B = 35.65 MB.  v aliases its head:
  // vtrans (reads v) completes before flash (writes opart) starts.
  bf16* v = opart;
  // total ws use ~47.6 MiB

  wt_kernel<<<dim3(16, 2, 3), 256, 0, stream>>>(wq, wk, wv, wt);
  qkv_kernel<<<dim3(512), 256, 0, stream>>>(x, wt, q, k, v);
  vtrans_kernel<<<dim3(32, 2, 8), 256, 0, stream>>>(v, vt);
  flash_kernel<<<dim3(32, 8, 16), 128, 0, stream>>>(q, k, vt, opart, lpart);
  combine_kernel<<<dim3(128, 8), 256, 0, stream>>>(opart, lpart, out);
}

// Round 6
// 240.574 us; speedup vs baseline: 1.0437x; 1.0437x over previous
//
#include <hip/hip_runtime.h>

#define BB 8
#define TT 2048
#define EE 1024
#define HH 128

typedef __bf16 bf16;
typedef __attribute__((ext_vector_type(8))) __bf16 bf16x8;
typedef __attribute__((ext_vector_type(4))) float f32x4;

// chunk=4 over 128-row q-blocks: ns(qb) = ((2qb+1)>>2)+1, off = prefix sum
__device__ __host__ inline int qb_off(int qb) {
  int h = qb >> 1;
  return qb + h * (h - 1) + ((qb & 1) ? h : 0);
}
#define NSLAB 72  // qb_off(16)

// ---- Wt[z*128+n][k] = W_z[k][n], fp32->bf16, LDS transpose ----
__global__ __launch_bounds__(256) void wt_kernel(const float* __restrict__ wq,
                                                 const float* __restrict__ wk,
                                                 const float* __restrict__ wv,
                                                 bf16* __restrict__ wt) {
  __shared__ float tile[64][65];
  const int z = blockIdx.z;
  const float* w = (z == 0) ? wq : ((z == 1) ? wk : wv);
  const int k0 = blockIdx.x * 64;
  const int h0 = blockIdx.y * 64;
  const int c = threadIdx.x & 63;
  const int r0 = threadIdx.x >> 6;
#pragma unroll
  for (int i = 0; i < 16; ++i) {
    int tt = r0 + i * 4;
    tile[tt][c] = w[(size_t)(k0 + tt) * HH + h0 + c];
  }
  __syncthreads();
#pragma unroll
  for (int i = 0; i < 16; ++i) {
    int hh = r0 + i * 4;
    wt[((size_t)(z * HH + h0 + hh)) * EE + k0 + c] = (bf16)tile[c][hh];
  }
}

// ---- fused qkv GEMM, direct loads + k-step software pipeline ----
// block = 4 waves, 32 rows x 384 cols; wave = 32 rows x 96 cols.
__global__ __launch_bounds__(256, 2) void qkv_kernel(const float* __restrict__ x,
                                                     const bf16* __restrict__ wt,
                                                     bf16* __restrict__ q,
                                                     bf16* __restrict__ k,
                                                     bf16* __restrict__ v) {
  const int lane = threadIdx.x & 63;
  const int wave = threadIdx.x >> 6;
  const int l16 = lane & 15;
  const int quad = lane >> 4;
  const int row0 = blockIdx.x * 32;

  const float* xb = x + (size_t)(row0 + l16) * EE + quad * 8;
  const bf16* wb = wt + (size_t)(wave * 96 + l16) * EE + quad * 8;

  f32x4 acc[2][6];
#pragma unroll
  for (int rg = 0; rg < 2; ++rg)
#pragma unroll
    for (int nt = 0; nt < 6; ++nt) acc[rg][nt] = f32x4{0.f, 0.f, 0.f, 0.f};

  // prefetch k-step 0
  f32x4 na0 = *(const f32x4*)(xb);
  f32x4 na1 = *(const f32x4*)(xb + 4);
  f32x4 na2 = *(const f32x4*)(xb + (size_t)16 * EE);
  f32x4 na3 = *(const f32x4*)(xb + (size_t)16 * EE + 4);
  bf16x8 nb[6];
#pragma unroll
  for (int j = 0; j < 6; ++j) nb[j] = *(const bf16x8*)(wb + (size_t)(j * 16) * EE);

  for (int ks = 0; ks < EE / 32; ++ks) {
    f32x4 a0 = na0, a1 = na1, a2 = na2, a3 = na3;
    bf16x8 b0 = nb[0], b1 = nb[1], b2 = nb[2], b3 = nb[3], b4 = nb[4], b5 = nb[5];
    if (ks < EE / 32 - 1) {  // issue next k-step loads before MFMAs
      na0 = *(const f32x4*)(xb + (ks + 1) * 32);
      na1 = *(const f32x4*)(xb + (ks + 1) * 32 + 4);
      na2 = *(const f32x4*)(xb + (size_t)16 * EE + (ks + 1) * 32);
      na3 = *(const f32x4*)(xb + (size_t)16 * EE + (ks + 1) * 32 + 4);
#pragma unroll
      for (int j = 0; j < 6; ++j)
        nb[j] = *(const bf16x8*)(wb + (size_t)(j * 16) * EE + (ks + 1) * 32);
    }
    bf16x8 af0, af1;
#pragma unroll
    for (int j = 0; j < 4; ++j) {
      af0[j] = (bf16)a0[j]; af0[j + 4] = (bf16)a1[j];
      af1[j] = (bf16)a2[j]; af1[j + 4] = (bf16)a3[j];
    }
    acc[0][0] = __builtin_amdgcn_mfma_f32_16x16x32_bf16(af0, b0, acc[0][0], 0, 0, 0);
    acc[1][0] = __builtin_amdgcn_mfma_f32_16x16x32_bf16(af1, b0, acc[1][0], 0, 0, 0);
    acc[0][1] = __builtin_amdgcn_mfma_f32_16x16x32_bf16(af0, b1, acc[0][1], 0, 0, 0);
    acc[1][1] = __builtin_amdgcn_mfma_f32_16x16x32_bf16(af1, b1, acc[1][1], 0, 0, 0);
    acc[0][2] = __builtin_amdgcn_mfma_f32_16x16x32_bf16(af0, b2, acc[0][2], 0, 0, 0);
    acc[1][2] = __builtin_amdgcn_mfma_f32_16x16x32_bf16(af1, b2, acc[1][2], 0, 0, 0);
    acc[0][3] = __builtin_amdgcn_mfma_f32_16x16x32_bf16(af0, b3, acc[0][3], 0, 0, 0);
    acc[1][3] = __builtin_amdgcn_mfma_f32_16x16x32_bf16(af1, b3, acc[1][3], 0, 0, 0);
    acc[0][4] = __builtin_amdgcn_mfma_f32_16x16x32_bf16(af0, b4, acc[0][4], 0, 0, 0);
    acc[1][4] = __builtin_amdgcn_mfma_f32_16x16x32_bf16(af1, b4, acc[1][4], 0, 0, 0);
    acc[0][5] = __builtin_amdgcn_mfma_f32_16x16x32_bf16(af0, b5, acc[0][5], 0, 0, 0);
    acc[1][5] = __builtin_amdgcn_mfma_f32_16x16x32_bf16(af1, b5, acc[1][5], 0, 0, 0);
  }

  bf16* outp[3] = {q, k, v};
#pragma unroll
  for (int rg = 0; rg < 2; ++rg)
#pragma unroll
    for (int nt = 0; nt < 6; ++nt) {
      int col = wave * 96 + nt * 16 + l16;
      int z = col >> 7;
      int n = col & 127;
#pragma unroll
      for (int r = 0; r < 4; ++r) {
        int row = row0 + rg * 16 + quad * 4 + r;
        outp[z][(size_t)row * HH + n] = (bf16)acc[rg][nt][r];
      }
    }
}

// ---- vt[b][h][t] = v[b][t][h] ----
__global__ __launch_bounds__(256) void vtrans_kernel(const bf16* __restrict__ v,
                                                     bf16* __restrict__ vt) {
  __shared__ bf16 tile[64][65];
  const int b = blockIdx.z;
  const int t0 = blockIdx.x * 64;
  const int h0 = blockIdx.y * 64;
  const int c = threadIdx.x & 63;
  const int r0 = threadIdx.x >> 6;
#pragma unroll
  for (int i = 0; i < 16; ++i) {
    int tt = r0 + i * 4;
    tile[tt][c] = v[((size_t)(b * TT + t0 + tt)) * HH + h0 + c];
  }
  __syncthreads();
#pragma unroll
  for (int i = 0; i < 16; ++i) {
    int hh = r0 + i * 4;
    vt[((size_t)(b * HH + h0 + hh)) * TT + t0 + c] = tile[c][hh];
  }
}

// ---- flash: 4 waves / 128 q-rows, chunk=4, no-max softmax, V-hoist ----
__global__ __launch_bounds__(256, 2) void flash_kernel(const bf16* __restrict__ q,
                                                       const bf16* __restrict__ k,
                                                       const bf16* __restrict__ vt,
                                                       bf16* __restrict__ opart,
                                                       float* __restrict__ lpart) {
  const int qb = blockIdx.x;  // 128-row group, 0..15
  const int b = blockIdx.y;
  const int s = blockIdx.z;
  const int smax = (2 * qb + 1) >> 2;
  if (s > smax) return;
  const int kt0 = s * 4;
  const int kt1 = min(kt0 + 3, 2 * qb + 1);

  const int lane = threadIdx.x & 63;
  const int wave = threadIdx.x >> 6;
  const int l16 = lane & 15;
  const int quad = lane >> 4;
  const int wrow0 = qb * 128 + wave * 32;

  __shared__ float pbuf[4][32 * 68];
  float* pb = &pbuf[wave][0];

  bf16x8 qf[2][4];
#pragma unroll
  for (int rg = 0; rg < 2; ++rg) {
    const bf16* qbp = q + (size_t)(b * TT + wrow0 + rg * 16 + l16) * HH + quad * 8;
#pragma unroll
    for (int ks = 0; ks < 4; ++ks) qf[rg][ks] = *(const bf16x8*)(qbp + ks * 32);
  }

  f32x4 O[2][8];
#pragma unroll
  for (int rg = 0; rg < 2; ++rg)
#pragma unroll
    for (int nt = 0; nt < 8; ++nt) O[rg][nt] = f32x4{0.f, 0.f, 0.f, 0.f};
  f32x4 O9[2] = {f32x4{0.f, 0.f, 0.f, 0.f}, f32x4{0.f, 0.f, 0.f, 0.f}};

  bf16x8 ones;
  {
    bf16 ov = (l16 == 0) ? (bf16)1.0f : (bf16)0.0f;
#pragma unroll
    for (int j = 0; j < 8; ++j) ones[j] = ov;
  }

  const float c_ = 0.12753257680406733f;  // log2(e)/sqrt(128)

  for (int kt = kt0; kt <= kt1; ++kt) {
    f32x4 S[2][4];
#pragma unroll
    for (int rg = 0; rg < 2; ++rg)
#pragma unroll
      for (int nt = 0; nt < 4; ++nt) S[rg][nt] = f32x4{0.f, 0.f, 0.f, 0.f};
    const bf16* kb = k + (size_t)(b * TT + kt * 64 + l16) * HH + quad * 8;
#pragma unroll
    for (int nt = 0; nt < 4; ++nt) {
      bf16x8 kf[4];
#pragma unroll
      for (int ks = 0; ks < 4; ++ks)
        kf[ks] = *(const bf16x8*)(kb + (size_t)nt * 16 * HH + ks * 32);
#pragma unroll
      for (int ks = 0; ks < 4; ++ks) {
        S[0][nt] = __builtin_amdgcn_mfma_f32_16x16x32_bf16(qf[0][ks], kf[ks], S[0][nt], 0, 0, 0);
        S[1][nt] = __builtin_amdgcn_mfma_f32_16x16x32_bf16(qf[1][ks], kf[ks], S[1][nt], 0, 0, 0);
      }
    }

    // hoist V(ks2=0) loads: latency overlaps exp + LDS round trip
    const bf16* vb = vt + (size_t)(b * HH + l16) * TT + kt * 64 + quad * 8;
    bf16x8 vf0[8];
#pragma unroll
    for (int nt = 0; nt < 8; ++nt)
      vf0[nt] = *(const bf16x8*)(vb + (size_t)nt * 16 * TT);

#pragma unroll
    for (int rg = 0; rg < 2; ++rg)
#pragma unroll
      for (int nt = 0; nt < 4; ++nt) {
        int col = kt * 64 + nt * 16 + l16;
#pragma unroll
        for (int r = 0; r < 4; ++r) {
          int row = wrow0 + rg * 16 + quad * 4 + r;
          float p = (col <= row) ? exp2f(S[rg][nt][r] * c_) : 0.f;
          pb[(rg * 16 + quad * 4 + r) * 68 + nt * 16 + l16] = p;
        }
      }
    __asm__ volatile("s_waitcnt lgkmcnt(0)" ::: "memory");

    // ks2 = 0 (uses hoisted vf0)
    {
      bf16x8 af[2];
#pragma unroll
      for (int rg = 0; rg < 2; ++rg) {
        const float* pr = &pb[(rg * 16 + l16) * 68 + quad * 8];
        f32x4 a0 = *(const f32x4*)pr;
        f32x4 a1 = *(const f32x4*)(pr + 4);
#pragma unroll
        for (int j = 0; j < 4; ++j) { af[rg][j] = (bf16)a0[j]; af[rg][j + 4] = (bf16)a1[j]; }
      }
#pragma unroll
      for (int nt = 0; nt < 8; ++nt) {
        O[0][nt] = __builtin_amdgcn_mfma_f32_16x16x32_bf16(af[0], vf0[nt], O[0][nt], 0, 0, 0);
        O[1][nt] = __builtin_amdgcn_mfma_f32_16x16x32_bf16(af[1], vf0[nt], O[1][nt], 0, 0, 0);
      }
      O9[0] = __builtin_amdgcn_mfma_f32_16x16x32_bf16(af[0], ones, O9[0], 0, 0, 0);
      O9[1] = __builtin_amdgcn_mfma_f32_16x16x32_bf16(af[1], ones, O9[1], 0, 0, 0);
    }
    // ks2 = 1 (inline V loads)
    {
      bf16x8 af[2];
#pragma unroll
      for (int rg = 0; rg < 2; ++rg) {
        const float* pr = &pb[(rg * 16 + l16) * 68 + 32 + quad * 8];
        f32x4 a0 = *(const f32x4*)pr;
        f32x4 a1 = *(const f32x4*)(pr + 4);
#pragma unroll
        for (int j = 0; j < 4; ++j) { af[rg][j] = (bf16)a0[j]; af[rg][j + 4] = (bf16)a1[j]; }
      }
#pragma unroll
      for (int nt = 0; nt < 8; ++nt) {
        bf16x8 vf = *(const bf16x8*)(vb + (size_t)nt * 16 * TT + 32);
        O[0][nt] = __builtin_amdgcn_mfma_f32_16x16x32_bf16(af[0], vf, O[0][nt], 0, 0, 0);
        O[1][nt] = __builtin_amdgcn_mfma_f32_16x16x32_bf16(af[1], vf, O[1][nt], 0, 0, 0);
      }
      O9[0] = __builtin_amdgcn_mfma_f32_16x16x32_bf16(af[0], ones, O9[0], 0, 0, 0);
      O9[1] = __builtin_amdgcn_mfma_f32_16x16x32_bf16(af[1], ones, O9[1], 0, 0, 0);
    }
    __asm__ volatile("s_waitcnt lgkmcnt(0)" ::: "memory");  // pb reuse next kt
  }

  const size_t slab = (size_t)(b * NSLAB + qb_off(qb) + s);
  bf16* op = opart + slab * (128 * 128);
#pragma unroll
  for (int rg = 0; rg < 2; ++rg)
#pragma unroll
    for (int nt = 0; nt < 8; ++nt)
#pragma unroll
      for (int r = 0; r < 4; ++r) {
        int row = wave * 32 + rg * 16 + quad * 4 + r;
        op[row * 128 + nt * 16 + l16] = (bf16)O[rg][nt][r];
      }
  if (l16 == 0) {
#pragma unroll
    for (int rg = 0; rg < 2; ++rg)
#pragma unroll
      for (int r = 0; r < 4; ++r)
        lpart[slab * 128 + wave * 32 + rg * 16 + quad * 4 + r] = O9[rg][r];
  }
}

// ---- combine: 1024 blocks, unrolled-by-4 s-loop ----
__global__ __launch_bounds__(256) void combine_kernel(const bf16* __restrict__ opart,
                                                      const float* __restrict__ lpart,
                                                      float* __restrict__ out) {
  const int qt16 = blockIdx.x;  // 16-row group, 0..127
  const int b = blockIdx.y;
  const int row = threadIdx.x >> 4;
  const int colo = (threadIdx.x & 15) * 8;
  const int qb = qt16 >> 3;
  const int srow = (qt16 & 7) * 16 + row;  // row within 128-row slab
  const int ns = ((2 * qb + 1) >> 2) + 1;  // 1..8
  const size_t slab0 = (size_t)(b * NSLAB + qb_off(qb));

  float acc[8];
#pragma unroll
  for (int j = 0; j < 8; ++j) acc[j] = 0.f;
  float L = 0.f;

  int s = 0;
  for (; s + 4 <= ns; s += 4) {
    float l0 = lpart[(slab0 + s + 0) * 128 + srow];
    float l1 = lpart[(slab0 + s + 1) * 128 + srow];
    float l2 = lpart[(slab0 + s + 2) * 128 + srow];
    float l3 = lpart[(slab0 + s + 3) * 128 + srow];
    bf16x8 v0 = *(const bf16x8*)(opart + (slab0 + s + 0) * (128 * 128) + srow * 128 + colo);
    bf16x8 v1 = *(const bf16x8*)(opart + (slab0 + s + 1) * (128 * 128) + srow * 128 + colo);
    bf16x8 v2 = *(const bf16x8*)(opart + (slab0 + s + 2) * (128 * 128) + srow * 128 + colo);
    bf16x8 v3 = *(const bf16x8*)(opart + (slab0 + s + 3) * (128 * 128) + srow * 128 + colo);
    L += (l0 + l1) + (l2 + l3);
#pragma unroll
    for (int j = 0; j < 8; ++j)
      acc[j] += ((float)v0[j] + (float)v1[j]) + ((float)v2[j] + (float)v3[j]);
  }
  for (; s < ns; ++s) {
    L += lpart[(slab0 + s) * 128 + srow];
    bf16x8 ov = *(const bf16x8*)(opart + (slab0 + s) * (128 * 128) + srow * 128 + colo);
#pragma unroll
    for (int j = 0; j < 8; ++j) acc[j] += (float)ov[j];
  }
  float invL = 1.f / L;
  float* o = out + ((size_t)(b * TT + qt16 * 16 + row)) * HH + colo;
  f32x4 o0, o1;
#pragma unroll
  for (int j = 0; j < 4; ++j) { o0[j] = acc[j] * invL; o1[j] = acc[j + 4] * invL; }
  *(f32x4*)o = o0;
  *(f32x4*)(o + 4) = o1;
}

extern "C" void kernel_launch(void* const* d_in, const int* in_sizes, int n_in,
                              void* d_out, int out_size, void* d_ws, size_t ws_size,
                              hipStream_t stream) {
  const float* x = (const float*)d_in[0];
  const float* wq = (const float*)d_in[1];
  const float* wk = (const float*)d_in[2];
  const float* wv = (const float*)d_in[3];
  float* out = (float*)d_out;

  char* ws = (char*)d_ws;
  const size_t NE = (size_t)BB * TT * HH;  // 2,097,152
  bf16* wt = (bf16*)ws;                    // 768 KB
  bf16* q = (bf16*)(ws + (1 << 20));       // 4 MB each
  bf16* k = q + NE;
  bf16* v = k + NE;
  bf16* vt = v + NE;
  bf16* opart = vt + NE;                   // 576 slabs * 16384 * 2B = 18.9 MB
  float* lpart = (float*)(opart + (size_t)(BB * NSLAB) * 128 * 128);  // 295 KB

  wt_kernel<<<dim3(16, 2, 3), 256, 0, stream>>>(wq, wk, wv, wt);
  qkv_kernel<<<dim3(512), 256, 0, stream>>>(x, wt, q, k, v);
  vtrans_kernel<<<dim3(32, 2, 8), 256, 0, stream>>>(v, vt);
  flash_kernel<<<dim3(16, 8, 8), 256, 0, stream>>>(q, k, vt, opart, lpart);
  combine_kernel<<<dim3(128, 8), 256, 0, stream>>>(opart, lpart, out);
}

// Round 7
// 204.121 us; speedup vs baseline: 1.2300x; 1.1786x over previous
//
#include <hip/hip_runtime.h>

#define BB 8
#define TT 2048
#define EE 1024
#define HH 128

typedef __bf16 bf16;
typedef __attribute__((ext_vector_type(8))) __bf16 bf16x8;
typedef __attribute__((ext_vector_type(4))) __bf16 bf16x4;
typedef __attribute__((ext_vector_type(4))) float f32x4;

// chunk=4 over 128-row q-blocks: ns(qb) = ((2qb+1)>>2)+1, off = prefix sum
__device__ __host__ inline int qb_off(int qb) {
  int h = qb >> 1;
  return qb + h * (h - 1) + ((qb & 1) ? h : 0);
}
#define NSLAB 72  // qb_off(16); valid (qb,s) pairs per batch

// ---- Wt[z*128+n][k] = W_z[k][n], fp32->bf16, LDS transpose ----
__global__ __launch_bounds__(256) void wt_kernel(const float* __restrict__ wq,
                                                 const float* __restrict__ wk,
                                                 const float* __restrict__ wv,
                                                 bf16* __restrict__ wt) {
  __shared__ float tile[64][65];
  const int z = blockIdx.z;
  const float* w = (z == 0) ? wq : ((z == 1) ? wk : wv);
  const int k0 = blockIdx.x * 64;
  const int h0 = blockIdx.y * 64;
  const int c = threadIdx.x & 63;
  const int r0 = threadIdx.x >> 6;
#pragma unroll
  for (int i = 0; i < 16; ++i) {
    int tt = r0 + i * 4;
    tile[tt][c] = w[(size_t)(k0 + tt) * HH + h0 + c];
  }
  __syncthreads();
#pragma unroll
  for (int i = 0; i < 16; ++i) {
    int hh = r0 + i * 4;
    wt[((size_t)(z * HH + h0 + hh)) * EE + k0 + c] = (bf16)tile[c][hh];
  }
}

// ---- fused qkv GEMM ----
// block = 4 waves, 32 rows x 384 cols. x staged to LDS in two K-halves with
// fully-coalesced row loads (channel-spread), then barrier-free MFMA loop.
__global__ __launch_bounds__(256, 2) void qkv_kernel(const float* __restrict__ x,
                                                     const bf16* __restrict__ wt,
                                                     bf16* __restrict__ q,
                                                     bf16* __restrict__ k,
                                                     bf16* __restrict__ v) {
  __shared__ bf16 xs[32 * 520];  // 32 rows x 512 k, stride 520 (33.3 KB)
  const int tid = threadIdx.x;
  const int lane = tid & 63;
  const int wave = tid >> 6;
  const int l16 = lane & 15;
  const int quad = lane >> 4;
  const int row0 = blockIdx.x * 32;

  const bf16* wb = wt + (size_t)(wave * 96 + l16) * EE + quad * 8;
  const int srow2 = tid >> 7;        // 0..1
  const int scol = (tid & 127) * 4;  // 0..508, lanes contiguous over a row

  f32x4 acc[2][6];
#pragma unroll
  for (int rg = 0; rg < 2; ++rg)
#pragma unroll
    for (int nt = 0; nt < 6; ++nt) acc[rg][nt] = f32x4{0.f, 0.f, 0.f, 0.f};

#pragma unroll
  for (int half = 0; half < 2; ++half) {
    if (half) __syncthreads();  // all waves done reading xs before restage
#pragma unroll 4
    for (int i = 0; i < 16; ++i) {
      int row = i * 2 + srow2;
      f32x4 xv = *(const f32x4*)(x + (size_t)(row0 + row) * EE + half * 512 + scol);
      bf16x4 xb;
#pragma unroll
      for (int j = 0; j < 4; ++j) xb[j] = (bf16)xv[j];
      *(bf16x4*)&xs[row * 520 + scol] = xb;
    }
    __syncthreads();

#pragma unroll
    for (int ks = 0; ks < 16; ++ks) {
      bf16x8 af0 = *(const bf16x8*)&xs[l16 * 520 + ks * 32 + quad * 8];
      bf16x8 af1 = *(const bf16x8*)&xs[(16 + l16) * 520 + ks * 32 + quad * 8];
#pragma unroll
      for (int nt = 0; nt < 6; ++nt) {
        bf16x8 bfr = *(const bf16x8*)(wb + (size_t)(nt * 16) * EE + half * 512 + ks * 32);
        acc[0][nt] = __builtin_amdgcn_mfma_f32_16x16x32_bf16(af0, bfr, acc[0][nt], 0, 0, 0);
        acc[1][nt] = __builtin_amdgcn_mfma_f32_16x16x32_bf16(af1, bfr, acc[1][nt], 0, 0, 0);
      }
    }
  }

  bf16* outp[3] = {q, k, v};
#pragma unroll
  for (int rg = 0; rg < 2; ++rg)
#pragma unroll
    for (int nt = 0; nt < 6; ++nt) {
      int col = wave * 96 + nt * 16 + l16;
      int z = col >> 7;
      int n = col & 127;
#pragma unroll
      for (int r = 0; r < 4; ++r) {
        int row = row0 + rg * 16 + quad * 4 + r;
        outp[z][(size_t)row * HH + n] = (bf16)acc[rg][nt][r];
      }
    }
}

// ---- vt[b][h][t] = v[b][t][h]; grid (b, t0, h0): id%8 = b -> XCD-pinned ----
__global__ __launch_bounds__(256) void vtrans_kernel(const bf16* __restrict__ v,
                                                     bf16* __restrict__ vt) {
  __shared__ bf16 tile[64][65];
  const int b = blockIdx.x;
  const int t0 = blockIdx.y * 64;
  const int h0 = blockIdx.z * 64;
  const int c = threadIdx.x & 63;
  const int r0 = threadIdx.x >> 6;
#pragma unroll
  for (int i = 0; i < 16; ++i) {
    int tt = r0 + i * 4;
    tile[tt][c] = v[((size_t)(b * TT + t0 + tt)) * HH + h0 + c];
  }
  __syncthreads();
#pragma unroll
  for (int i = 0; i < 16; ++i) {
    int hh = r0 + i * 4;
    vt[((size_t)(b * HH + h0 + hh)) * TT + t0 + c] = tile[c][hh];
  }
}

// ---- flash: 4 waves / 128 q-rows, chunk=4, no-max softmax, V-hoist ----
// 1-D grid of 8*72=576 valid blocks; id%8 = b pins each batch to one XCD
// (q/k/vt working set ~3 MB < 4 MB per-XCD L2).
__global__ __launch_bounds__(256, 2) void flash_kernel(const bf16* __restrict__ q,
                                                       const bf16* __restrict__ k,
                                                       const bf16* __restrict__ vt,
                                                       bf16* __restrict__ opart,
                                                       float* __restrict__ lpart) {
  const int b = blockIdx.x & 7;
  int j = blockIdx.x >> 3;  // 0..71 -> (qb, s)
  int qb = 0, ns = 1;
  while (j >= ns) { j -= ns; ++qb; ns = ((2 * qb + 1) >> 2) + 1; }
  const int s = j;
  const int kt0 = s * 4;
  const int kt1 = min(kt0 + 3, 2 * qb + 1);

  const int lane = threadIdx.x & 63;
  const int wave = threadIdx.x >> 6;
  const int l16 = lane & 15;
  const int quad = lane >> 4;
  const int wrow0 = qb * 128 + wave * 32;

  __shared__ float pbuf[4][32 * 68];
  float* pb = &pbuf[wave][0];

  bf16x8 qf[2][4];
#pragma unroll
  for (int rg = 0; rg < 2; ++rg) {
    const bf16* qbp = q + (size_t)(b * TT + wrow0 + rg * 16 + l16) * HH + quad * 8;
#pragma unroll
    for (int ks = 0; ks < 4; ++ks) qf[rg][ks] = *(const bf16x8*)(qbp + ks * 32);
  }

  f32x4 O[2][8];
#pragma unroll
  for (int rg = 0; rg < 2; ++rg)
#pragma unroll
    for (int nt = 0; nt < 8; ++nt) O[rg][nt] = f32x4{0.f, 0.f, 0.f, 0.f};
  f32x4 O9[2] = {f32x4{0.f, 0.f, 0.f, 0.f}, f32x4{0.f, 0.f, 0.f, 0.f}};

  bf16x8 ones;
  {
    bf16 ov = (l16 == 0) ? (bf16)1.0f : (bf16)0.0f;
#pragma unroll
    for (int j2 = 0; j2 < 8; ++j2) ones[j2] = ov;
  }

  const float c_ = 0.12753257680406733f;  // log2(e)/sqrt(128)

  for (int kt = kt0; kt <= kt1; ++kt) {
    f32x4 S[2][4];
#pragma unroll
    for (int rg = 0; rg < 2; ++rg)
#pragma unroll
      for (int nt = 0; nt < 4; ++nt) S[rg][nt] = f32x4{0.f, 0.f, 0.f, 0.f};
    const bf16* kb = k + (size_t)(b * TT + kt * 64 + l16) * HH + quad * 8;
#pragma unroll
    for (int nt = 0; nt < 4; ++nt) {
      bf16x8 kf[4];
#pragma unroll
      for (int ks = 0; ks < 4; ++ks)
        kf[ks] = *(const bf16x8*)(kb + (size_t)nt * 16 * HH + ks * 32);
#pragma unroll
      for (int ks = 0; ks < 4; ++ks) {
        S[0][nt] = __builtin_amdgcn_mfma_f32_16x16x32_bf16(qf[0][ks], kf[ks], S[0][nt], 0, 0, 0);
        S[1][nt] = __builtin_amdgcn_mfma_f32_16x16x32_bf16(qf[1][ks], kf[ks], S[1][nt], 0, 0, 0);
      }
    }

    const bf16* vb = vt + (size_t)(b * HH + l16) * TT + kt * 64 + quad * 8;
    bf16x8 vf0[8];
#pragma unroll
    for (int nt = 0; nt < 8; ++nt)
      vf0[nt] = *(const bf16x8*)(vb + (size_t)nt * 16 * TT);

#pragma unroll
    for (int rg = 0; rg < 2; ++rg)
#pragma unroll
      for (int nt = 0; nt < 4; ++nt) {
        int col = kt * 64 + nt * 16 + l16;
#pragma unroll
        for (int r = 0; r < 4; ++r) {
          int row = wrow0 + rg * 16 + quad * 4 + r;
          float p = (col <= row) ? exp2f(S[rg][nt][r] * c_) : 0.f;
          pb[(rg * 16 + quad * 4 + r) * 68 + nt * 16 + l16] = p;
        }
      }
    __asm__ volatile("s_waitcnt lgkmcnt(0)" ::: "memory");

    {  // ks2 = 0 (hoisted V)
      bf16x8 af[2];
#pragma unroll
      for (int rg = 0; rg < 2; ++rg) {
        const float* pr = &pb[(rg * 16 + l16) * 68 + quad * 8];
        f32x4 a0 = *(const f32x4*)pr;
        f32x4 a1 = *(const f32x4*)(pr + 4);
#pragma unroll
        for (int j2 = 0; j2 < 4; ++j2) { af[rg][j2] = (bf16)a0[j2]; af[rg][j2 + 4] = (bf16)a1[j2]; }
      }
#pragma unroll
      for (int nt = 0; nt < 8; ++nt) {
        O[0][nt] = __builtin_amdgcn_mfma_f32_16x16x32_bf16(af[0], vf0[nt], O[0][nt], 0, 0, 0);
        O[1][nt] = __builtin_amdgcn_mfma_f32_16x16x32_bf16(af[1], vf0[nt], O[1][nt], 0, 0, 0);
      }
      O9[0] = __builtin_amdgcn_mfma_f32_16x16x32_bf16(af[0], ones, O9[0], 0, 0, 0);
      O9[1] = __builtin_amdgcn_mfma_f32_16x16x32_bf16(af[1], ones, O9[1], 0, 0, 0);
    }
    {  // ks2 = 1
      bf16x8 af[2];
#pragma unroll
      for (int rg = 0; rg < 2; ++rg) {
        const float* pr = &pb[(rg * 16 + l16) * 68 + 32 + quad * 8];
        f32x4 a0 = *(const f32x4*)pr;
        f32x4 a1 = *(const f32x4*)(pr + 4);
#pragma unroll
        for (int j2 = 0; j2 < 4; ++j2) { af[rg][j2] = (bf16)a0[j2]; af[rg][j2 + 4] = (bf16)a1[j2]; }
      }
#pragma unroll
      for (int nt = 0; nt < 8; ++nt) {
        bf16x8 vf = *(const bf16x8*)(vb + (size_t)nt * 16 * TT + 32);
        O[0][nt] = __builtin_amdgcn_mfma_f32_16x16x32_bf16(af[0], vf, O[0][nt], 0, 0, 0);
        O[1][nt] = __builtin_amdgcn_mfma_f32_16x16x32_bf16(af[1], vf, O[1][nt], 0, 0, 0);
      }
      O9[0] = __builtin_amdgcn_mfma_f32_16x16x32_bf16(af[0], ones, O9[0], 0, 0, 0);
      O9[1] = __builtin_amdgcn_mfma_f32_16x16x32_bf16(af[1], ones, O9[1], 0, 0, 0);
    }
    __asm__ volatile("s_waitcnt lgkmcnt(0)" ::: "memory");
  }

  const size_t slab = (size_t)(b * NSLAB + qb_off(qb) + s);
  bf16* op = opart + slab * (128 * 128);
#pragma unroll
  for (int rg = 0; rg < 2; ++rg)
#pragma unroll
    for (int nt = 0; nt < 8; ++nt)
#pragma unroll
      for (int r = 0; r < 4; ++r) {
        int row = wave * 32 + rg * 16 + quad * 4 + r;
        op[row * 128 + nt * 16 + l16] = (bf16)O[rg][nt][r];
      }
  if (l16 == 0) {
#pragma unroll
    for (int rg = 0; rg < 2; ++rg)
#pragma unroll
      for (int r = 0; r < 4; ++r)
        lpart[slab * 128 + wave * 32 + rg * 16 + quad * 4 + r] = O9[rg][r];
  }
}

// ---- combine: grid (b, qt16, half) -> 2048 blocks of 128 thr, XCD-pinned ----
__global__ __launch_bounds__(128) void combine_kernel(const bf16* __restrict__ opart,
                                                      const float* __restrict__ lpart,
                                                      float* __restrict__ out) {
  const int b = blockIdx.x;
  const int qt16 = blockIdx.y;
  const int half = blockIdx.z;
  const int row = threadIdx.x >> 3;                    // 0..15
  const int colo = (threadIdx.x & 7) * 8 + half * 64;  // 8 cols
  const int qb = qt16 >> 3;
  const int srow = (qt16 & 7) * 16 + row;
  const int ns = ((2 * qb + 1) >> 2) + 1;  // 1..8
  const size_t slab0 = (size_t)(b * NSLAB + qb_off(qb));

  float acc[8];
#pragma unroll
  for (int j = 0; j < 8; ++j) acc[j] = 0.f;
  float L = 0.f;

  int s = 0;
  for (; s + 4 <= ns; s += 4) {
    float l0 = lpart[(slab0 + s + 0) * 128 + srow];
    float l1 = lpart[(slab0 + s + 1) * 128 + srow];
    float l2 = lpart[(slab0 + s + 2) * 128 + srow];
    float l3 = lpart[(slab0 + s + 3) * 128 + srow];
    bf16x8 v0 = *(const bf16x8*)(opart + (slab0 + s + 0) * (128 * 128) + srow * 128 + colo);
    bf16x8 v1 = *(const bf16x8*)(opart + (slab0 + s + 1) * (128 * 128) + srow * 128 + colo);
    bf16x8 v2 = *(const bf16x8*)(opart + (slab0 + s + 2) * (128 * 128) + srow * 128 + colo);
    bf16x8 v3 = *(const bf16x8*)(opart + (slab0 + s + 3) * (128 * 128) + srow * 128 + colo);
    L += (l0 + l1) + (l2 + l3);
#pragma unroll
    for (int j = 0; j < 8; ++j)
      acc[j] += ((float)v0[j] + (float)v1[j]) + ((float)v2[j] + (float)v3[j]);
  }
  for (; s < ns; ++s) {
    L += lpart[(slab0 + s) * 128 + srow];
    bf16x8 ov = *(const bf16x8*)(opart + (slab0 + s) * (128 * 128) + srow * 128 + colo);
#pragma unroll
    for (int j = 0; j < 8; ++j) acc[j] += (float)ov[j];
  }
  float invL = 1.f / L;
  float* o = out + ((size_t)(b * TT + qt16 * 16 + row)) * HH + colo;
  f32x4 o0, o1;
#pragma unroll
  for (int j = 0; j < 4; ++j) { o0[j] = acc[j] * invL; o1[j] = acc[j + 4] * invL; }
  *(f32x4*)o = o0;
  *(f32x4*)(o + 4) = o1;
}

extern "C" void kernel_launch(void* const* d_in, const int* in_sizes, int n_in,
                              void* d_out, int out_size, void* d_ws, size_t ws_size,
                              hipStream_t stream) {
  const float* x = (const float*)d_in[0];
  const float* wq = (const float*)d_in[1];
  const float* wk = (const float*)d_in[2];
  const float* wv = (const float*)d_in[3];
  float* out = (float*)d_out;

  char* ws = (char*)d_ws;
  const size_t NE = (size_t)BB * TT * HH;  // 2,097,152
  bf16* wt = (bf16*)ws;                    // 768 KB
  bf16* q = (bf16*)(ws + (1 << 20));       // 4 MB each
  bf16* k = q + NE;
  bf16* v = k + NE;
  bf16* vt = v + NE;
  bf16* opart = vt + NE;                   // 576 slabs * 16384 * 2B = 18.9 MB
  float* lpart = (float*)(opart + (size_t)(BB * NSLAB) * 128 * 128);  // 295 KB

  wt_kernel<<<dim3(16, 2, 3), 256, 0, stream>>>(wq, wk, wv, wt);
  qkv_kernel<<<dim3(512), 256, 0, stream>>>(x, wt, q, k, v);
  vtrans_kernel<<<dim3(8, 32, 2), 256, 0, stream>>>(v, vt);
  flash_kernel<<<dim3(576), 256, 0, stream>>>(q, k, vt, opart, lpart);
  combine_kernel<<<dim3(8, 128, 2), 128, 0, stream>>>(opart, lpart, out);
}

// Round 8
// 185.254 us; speedup vs baseline: 1.3553x; 1.1018x over previous
//
#include <hip/hip_runtime.h>

#define BB 8
#define TT 2048
#define EE 1024
#define HH 128

typedef __bf16 bf16;
typedef __attribute__((ext_vector_type(8))) __bf16 bf16x8;
typedef __attribute__((ext_vector_type(4))) __bf16 bf16x4;
typedef __attribute__((ext_vector_type(4))) float f32x4;

__device__ __host__ inline int qb_off(int qb) {
  int h = qb >> 1;
  return qb + h * (h - 1) + ((qb & 1) ? h : 0);
}
#define NSLAB 72  // qb_off(16); valid (qb,s) pairs per batch

__device__ inline void gload_lds16(const bf16* g, bf16* l) {
  __builtin_amdgcn_global_load_lds((const __attribute__((address_space(1))) unsigned int*)g,
                                   (__attribute__((address_space(3))) unsigned int*)l,
                                   16, 0, 0);
}

// ---- Wt[z*128+n][k] = W_z[k][n], fp32->bf16, LDS transpose ----
__global__ __launch_bounds__(256) void wt_kernel(const float* __restrict__ wq,
                                                 const float* __restrict__ wk,
                                                 const float* __restrict__ wv,
                                                 bf16* __restrict__ wt) {
  __shared__ float tile[64][65];
  const int z = blockIdx.z;
  const float* w = (z == 0) ? wq : ((z == 1) ? wk : wv);
  const int k0 = blockIdx.x * 64;
  const int h0 = blockIdx.y * 64;
  const int c = threadIdx.x & 63;
  const int r0 = threadIdx.x >> 6;
#pragma unroll
  for (int i = 0; i < 16; ++i) {
    int tt = r0 + i * 4;
    tile[tt][c] = w[(size_t)(k0 + tt) * HH + h0 + c];
  }
  __syncthreads();
#pragma unroll
  for (int i = 0; i < 16; ++i) {
    int hh = r0 + i * 4;
    wt[((size_t)(z * HH + h0 + hh)) * EE + k0 + c] = (bf16)tile[c][hh];
  }
}

// ---- x fp32 -> bf16 (memory-bound, coalesced) ----
__global__ __launch_bounds__(256) void xcvt_kernel(const float* __restrict__ x,
                                                   bf16* __restrict__ xb) {
  const size_t base = (size_t)blockIdx.x * 4096 + threadIdx.x * 4;
#pragma unroll
  for (int j = 0; j < 4; ++j) {
    size_t idx = base + j * 1024;
    f32x4 xv = *(const f32x4*)(x + idx);
    bf16x4 xo;
#pragma unroll
    for (int i = 0; i < 4; ++i) xo[i] = (bf16)xv[i];
    *(bf16x4*)(xb + idx) = xo;
  }
}

// ---- fused qkv GEMM, m97 structure ----
// grid (128,4): 128 M-tiles x 4 N-tiles of 96 fused cols. block = 4 waves;
// wave (wm,wn) computes 64x48. BK=32, A/B staged via global_load_lds w=16.
__global__ __launch_bounds__(256) void gemm_kernel(const bf16* __restrict__ xb,
                                                   const bf16* __restrict__ wt,
                                                   bf16* __restrict__ q,
                                                   bf16* __restrict__ k,
                                                   bf16* __restrict__ v) {
  __shared__ bf16 As[128 * 32];  // 8 KB, raw (global_load_lds needs lane-linear)
  __shared__ bf16 Bs[96 * 32];   // 6 KB
  const int tid = threadIdx.x;
  const int lane = tid & 63;
  const int wave = tid >> 6;
  const int l16 = lane & 15;
  const int quad = lane >> 4;
  const int wm = wave & 1;   // M half (64 rows)
  const int wn = wave >> 1;  // N half (48 cols)
  const int bm = blockIdx.x;
  const int ntile = blockIdx.y;

  const int trow = tid >> 2;        // 0..63
  const int tsub = (tid & 3) * 8;   // 0,8,16,24
  const bf16* gA = xb + (size_t)(bm * 128 + trow) * EE + tsub;
  const bf16* gB = wt + (size_t)(ntile * 96 + trow) * EE + tsub;

  f32x4 acc[4][3];
#pragma unroll
  for (int rg = 0; rg < 4; ++rg)
#pragma unroll
    for (int nt = 0; nt < 3; ++nt) acc[rg][nt] = f32x4{0.f, 0.f, 0.f, 0.f};

  for (int ks = 0; ks < EE / 32; ++ks) {
    // stage A (128x32): 2 rounds of 4 KB
    gload_lds16(gA + ks * 32, &As[wave * 512]);
    gload_lds16(gA + (size_t)64 * EE + ks * 32, &As[2048 + wave * 512]);
    // stage B (96x32): 1.5 rounds
    gload_lds16(gB + ks * 32, &Bs[wave * 512]);
    if (tid < 128)
      gload_lds16(gB + (size_t)64 * EE + ks * 32, &Bs[2048 + wave * 512]);
    __syncthreads();  // drains vmcnt(0): staging complete

    bf16x8 af[4], bf[3];
#pragma unroll
    for (int rg = 0; rg < 4; ++rg)
      af[rg] = *(const bf16x8*)&As[(wm * 64 + rg * 16 + l16) * 32 + quad * 8];
#pragma unroll
    for (int nt = 0; nt < 3; ++nt)
      bf[nt] = *(const bf16x8*)&Bs[(wn * 48 + nt * 16 + l16) * 32 + quad * 8];
#pragma unroll
    for (int rg = 0; rg < 4; ++rg)
#pragma unroll
      for (int nt = 0; nt < 3; ++nt)
        acc[rg][nt] = __builtin_amdgcn_mfma_f32_16x16x32_bf16(af[rg], bf[nt], acc[rg][nt], 0, 0, 0);
    __syncthreads();  // all waves done reading before restage
  }

  bf16* outp[3] = {q, k, v};
#pragma unroll
  for (int rg = 0; rg < 4; ++rg)
#pragma unroll
    for (int nt = 0; nt < 3; ++nt) {
      int col = ntile * 96 + wn * 48 + nt * 16 + l16;
      int z = col >> 7;
      int n = col & 127;
#pragma unroll
      for (int r = 0; r < 4; ++r) {
        int row = bm * 128 + wm * 64 + rg * 16 + quad * 4 + r;
        outp[z][(size_t)row * HH + n] = (bf16)acc[rg][nt][r];
      }
    }
}

// ---- vt[b][h][t] = v[b][t][h]; id%8 = b -> XCD-pinned ----
__global__ __launch_bounds__(256) void vtrans_kernel(const bf16* __restrict__ v,
                                                     bf16* __restrict__ vt) {
  __shared__ bf16 tile[64][65];
  const int b = blockIdx.x;
  const int t0 = blockIdx.y * 64;
  const int h0 = blockIdx.z * 64;
  const int c = threadIdx.x & 63;
  const int r0 = threadIdx.x >> 6;
#pragma unroll
  for (int i = 0; i < 16; ++i) {
    int tt = r0 + i * 4;
    tile[tt][c] = v[((size_t)(b * TT + t0 + tt)) * HH + h0 + c];
  }
  __syncthreads();
#pragma unroll
  for (int i = 0; i < 16; ++i) {
    int hh = r0 + i * 4;
    vt[((size_t)(b * HH + h0 + hh)) * TT + t0 + c] = tile[c][hh];
  }
}

// ---- flash: 4 waves / 128 q-rows, chunk=4, no-max softmax, V-hoist ----
__global__ __launch_bounds__(256, 2) void flash_kernel(const bf16* __restrict__ q,
                                                       const bf16* __restrict__ k,
                                                       const bf16* __restrict__ vt,
                                                       bf16* __restrict__ opart,
                                                       float* __restrict__ lpart) {
  const int b = blockIdx.x & 7;
  int j = blockIdx.x >> 3;  // 0..71 -> (qb, s)
  int qb = 0, ns = 1;
  while (j >= ns) { j -= ns; ++qb; ns = ((2 * qb + 1) >> 2) + 1; }
  const int s = j;
  const int kt0 = s * 4;
  const int kt1 = min(kt0 + 3, 2 * qb + 1);

  const int lane = threadIdx.x & 63;
  const int wave = threadIdx.x >> 6;
  const int l16 = lane & 15;
  const int quad = lane >> 4;
  const int wrow0 = qb * 128 + wave * 32;

  __shared__ float pbuf[4][32 * 68];
  float* pb = &pbuf[wave][0];

  bf16x8 qf[2][4];
#pragma unroll
  for (int rg = 0; rg < 2; ++rg) {
    const bf16* qbp = q + (size_t)(b * TT + wrow0 + rg * 16 + l16) * HH + quad * 8;
#pragma unroll
    for (int ks = 0; ks < 4; ++ks) qf[rg][ks] = *(const bf16x8*)(qbp + ks * 32);
  }

  f32x4 O[2][8];
#pragma unroll
  for (int rg = 0; rg < 2; ++rg)
#pragma unroll
    for (int nt = 0; nt < 8; ++nt) O[rg][nt] = f32x4{0.f, 0.f, 0.f, 0.f};
  f32x4 O9[2] = {f32x4{0.f, 0.f, 0.f, 0.f}, f32x4{0.f, 0.f, 0.f, 0.f}};

  bf16x8 ones;
  {
    bf16 ov = (l16 == 0) ? (bf16)1.0f : (bf16)0.0f;
#pragma unroll
    for (int j2 = 0; j2 < 8; ++j2) ones[j2] = ov;
  }

  const float c_ = 0.12753257680406733f;  // log2(e)/sqrt(128)

  for (int kt = kt0; kt <= kt1; ++kt) {
    f32x4 S[2][4];
#pragma unroll
    for (int rg = 0; rg < 2; ++rg)
#pragma unroll
      for (int nt = 0; nt < 4; ++nt) S[rg][nt] = f32x4{0.f, 0.f, 0.f, 0.f};
    const bf16* kb = k + (size_t)(b * TT + kt * 64 + l16) * HH + quad * 8;
#pragma unroll
    for (int nt = 0; nt < 4; ++nt) {
      bf16x8 kf[4];
#pragma unroll
      for (int ks = 0; ks < 4; ++ks)
        kf[ks] = *(const bf16x8*)(kb + (size_t)nt * 16 * HH + ks * 32);
#pragma unroll
      for (int ks = 0; ks < 4; ++ks) {
        S[0][nt] = __builtin_amdgcn_mfma_f32_16x16x32_bf16(qf[0][ks], kf[ks], S[0][nt], 0, 0, 0);
        S[1][nt] = __builtin_amdgcn_mfma_f32_16x16x32_bf16(qf[1][ks], kf[ks], S[1][nt], 0, 0, 0);
      }
    }

    const bf16* vb = vt + (size_t)(b * HH + l16) * TT + kt * 64 + quad * 8;
    bf16x8 vf0[8];
#pragma unroll
    for (int nt = 0; nt < 8; ++nt)
      vf0[nt] = *(const bf16x8*)(vb + (size_t)nt * 16 * TT);

#pragma unroll
    for (int rg = 0; rg < 2; ++rg)
#pragma unroll
      for (int nt = 0; nt < 4; ++nt) {
        int col = kt * 64 + nt * 16 + l16;
#pragma unroll
        for (int r = 0; r < 4; ++r) {
          int row = wrow0 + rg * 16 + quad * 4 + r;
          float p = (col <= row) ? exp2f(S[rg][nt][r] * c_) : 0.f;
          pb[(rg * 16 + quad * 4 + r) * 68 + nt * 16 + l16] = p;
        }
      }
    __asm__ volatile("s_waitcnt lgkmcnt(0)" ::: "memory");

    {  // ks2 = 0 (hoisted V)
      bf16x8 af[2];
#pragma unroll
      for (int rg = 0; rg < 2; ++rg) {
        const float* pr = &pb[(rg * 16 + l16) * 68 + quad * 8];
        f32x4 a0 = *(const f32x4*)pr;
        f32x4 a1 = *(const f32x4*)(pr + 4);
#pragma unroll
        for (int j2 = 0; j2 < 4; ++j2) { af[rg][j2] = (bf16)a0[j2]; af[rg][j2 + 4] = (bf16)a1[j2]; }
      }
#pragma unroll
      for (int nt = 0; nt < 8; ++nt) {
        O[0][nt] = __builtin_amdgcn_mfma_f32_16x16x32_bf16(af[0], vf0[nt], O[0][nt], 0, 0, 0);
        O[1][nt] = __builtin_amdgcn_mfma_f32_16x16x32_bf16(af[1], vf0[nt], O[1][nt], 0, 0, 0);
      }
      O9[0] = __builtin_amdgcn_mfma_f32_16x16x32_bf16(af[0], ones, O9[0], 0, 0, 0);
      O9[1] = __builtin_amdgcn_mfma_f32_16x16x32_bf16(af[1], ones, O9[1], 0, 0, 0);
    }
    {  // ks2 = 1
      bf16x8 af[2];
#pragma unroll
      for (int rg = 0; rg < 2; ++rg) {
        const float* pr = &pb[(rg * 16 + l16) * 68 + 32 + quad * 8];
        f32x4 a0 = *(const f32x4*)pr;
        f32x4 a1 = *(const f32x4*)(pr + 4);
#pragma unroll
        for (int j2 = 0; j2 < 4; ++j2) { af[rg][j2] = (bf16)a0[j2]; af[rg][j2 + 4] = (bf16)a1[j2]; }
      }
#pragma unroll
      for (int nt = 0; nt < 8; ++nt) {
        bf16x8 vf = *(const bf16x8*)(vb + (size_t)nt * 16 * TT + 32);
        O[0][nt] = __builtin_amdgcn_mfma_f32_16x16x32_bf16(af[0], vf, O[0][nt], 0, 0, 0);
        O[1][nt] = __builtin_amdgcn_mfma_f32_16x16x32_bf16(af[1], vf, O[1][nt], 0, 0, 0);
      }
      O9[0] = __builtin_amdgcn_mfma_f32_16x16x32_bf16(af[0], ones, O9[0], 0, 0, 0);
      O9[1] = __builtin_amdgcn_mfma_f32_16x16x32_bf16(af[1], ones, O9[1], 0, 0, 0);
    }
    __asm__ volatile("s_waitcnt lgkmcnt(0)" ::: "memory");
  }

  const size_t slab = (size_t)(b * NSLAB + qb_off(qb) + s);
  bf16* op = opart + slab * (128 * 128);
#pragma unroll
  for (int rg = 0; rg < 2; ++rg)
#pragma unroll
    for (int nt = 0; nt < 8; ++nt)
#pragma unroll
      for (int r = 0; r < 4; ++r) {
        int row = wave * 32 + rg * 16 + quad * 4 + r;
        op[row * 128 + nt * 16 + l16] = (bf16)O[rg][nt][r];
      }
  if (l16 == 0) {
#pragma unroll
    for (int rg = 0; rg < 2; ++rg)
#pragma unroll
      for (int r = 0; r < 4; ++r)
        lpart[slab * 128 + wave * 32 + rg * 16 + quad * 4 + r] = O9[rg][r];
  }
}

// ---- combine: grid (b, qt16, half) -> 2048 blocks of 128 thr ----
__global__ __launch_bounds__(128) void combine_kernel(const bf16* __restrict__ opart,
                                                      const float* __restrict__ lpart,
                                                      float* __restrict__ out) {
  const int b = blockIdx.x;
  const int qt16 = blockIdx.y;
  const int half = blockIdx.z;
  const int row = threadIdx.x >> 3;
  const int colo = (threadIdx.x & 7) * 8 + half * 64;
  const int qb = qt16 >> 3;
  const int srow = (qt16 & 7) * 16 + row;
  const int ns = ((2 * qb + 1) >> 2) + 1;  // 1..8
  const size_t slab0 = (size_t)(b * NSLAB + qb_off(qb));

  float acc[8];
#pragma unroll
  for (int j = 0; j < 8; ++j) acc[j] = 0.f;
  float L = 0.f;

  int s = 0;
  for (; s + 4 <= ns; s += 4) {
    float l0 = lpart[(slab0 + s + 0) * 128 + srow];
    float l1 = lpart[(slab0 + s + 1) * 128 + srow];
    float l2 = lpart[(slab0 + s + 2) * 128 + srow];
    float l3 = lpart[(slab0 + s + 3) * 128 + srow];
    bf16x8 v0 = *(const bf16x8*)(opart + (slab0 + s + 0) * (128 * 128) + srow * 128 + colo);
    bf16x8 v1 = *(const bf16x8*)(opart + (slab0 + s + 1) * (128 * 128) + srow * 128 + colo);
    bf16x8 v2 = *(const bf16x8*)(opart + (slab0 + s + 2) * (128 * 128) + srow * 128 + colo);
    bf16x8 v3 = *(const bf16x8*)(opart + (slab0 + s + 3) * (128 * 128) + srow * 128 + colo);
    L += (l0 + l1) + (l2 + l3);
#pragma unroll
    for (int j = 0; j < 8; ++j)
      acc[j] += ((float)v0[j] + (float)v1[j]) + ((float)v2[j] + (float)v3[j]);
  }
  for (; s < ns; ++s) {
    L += lpart[(slab0 + s) * 128 + srow];
    bf16x8 ov = *(const bf16x8*)(opart + (slab0 + s) * (128 * 128) + srow * 128 + colo);
#pragma unroll
    for (int j = 0; j < 8; ++j) acc[j] += (float)ov[j];
  }
  float invL = 1.f / L;
  float* o = out + ((size_t)(b * TT + qt16 * 16 + row)) * HH + colo;
  f32x4 o0, o1;
#pragma unroll
  for (int j = 0; j < 4; ++j) { o0[j] = acc[j] * invL; o1[j] = acc[j + 4] * invL; }
  *(f32x4*)o = o0;
  *(f32x4*)(o + 4) = o1;
}

extern "C" void kernel_launch(void* const* d_in, const int* in_sizes, int n_in,
                              void* d_out, int out_size, void* d_ws, size_t ws_size,
                              hipStream_t stream) {
  const float* x = (const float*)d_in[0];
  const float* wq = (const float*)d_in[1];
  const float* wk = (const float*)d_in[2];
  const float* wv = (const float*)d_in[3];
  float* out = (float*)d_out;

  char* ws = (char*)d_ws;
  const size_t NE = (size_t)BB * TT * HH;  // 2,097,152
  bf16* wt = (bf16*)ws;                    // 768 KB
  bf16* xb = (bf16*)(ws + (1 << 20));      // 32 MiB (16384x1024 bf16)
  bf16* q = (bf16*)(ws + (33 << 20));      // 4 MiB each
  bf16* k = q + NE;
  bf16* v = k + NE;
  bf16* vt = v + NE;
  // xb is dead after gemm; opart/lpart alias its region (19.2 MB < 32 MiB)
  bf16* opart = xb;
  float* lpart = (float*)(opart + (size_t)(BB * NSLAB) * 128 * 128);
  // total ws use: 49 MiB

  wt_kernel<<<dim3(16, 2, 3), 256, 0, stream>>>(wq, wk, wv, wt);
  xcvt_kernel<<<dim3(4096), 256, 0, stream>>>(x, xb);
  gemm_kernel<<<dim3(128, 4), 256, 0, stream>>>(xb, wt, q, k, v);
  vtrans_kernel<<<dim3(8, 32, 2), 256, 0, stream>>>(v, vt);
  flash_kernel<<<dim3(576), 256, 0, stream>>>(q, k, vt, opart, lpart);
  combine_kernel<<<dim3(8, 128, 2), 128, 0, stream>>>(opart, lpart, out);
}